// Round 13
// baseline (128.797 us; speedup 1.0000x reference)
//
#include <hip/hip_runtime.h>
#include <hip/hip_bf16.h>
#include <cstddef>

// Dims fixed by reference: B=2, S=2048, H=1024, NH=4, DH=256
constexpr int Bx = 2, Sx = 2048, Hx = 1024, NHx = 4, DHx = 256;
constexpr float RSQ = 0.0625f;   // 1/sqrt(256)

typedef __attribute__((ext_vector_type(8))) short    bf16x8;
typedef __attribute__((ext_vector_type(4))) float    f32x4;
typedef __attribute__((ext_vector_type(4))) unsigned u32x4;

__device__ __forceinline__ float logsigf(float x) {
  return (x >= 0.0f) ? -log1pf(expf(-x)) : x - log1pf(expf(x));
}
__device__ __forceinline__ unsigned short f2bf(float x) {  // RNE f32->bf16
  unsigned u = __builtin_bit_cast(unsigned, x);
  u = (u + 0x7fffu + ((u >> 16) & 1u)) >> 16;
  return (unsigned short)u;
}
__device__ __forceinline__ float bf2f(unsigned short u) {
  unsigned v = (unsigned)u << 16;
  return __builtin_bit_cast(float, v);
}
__device__ __forceinline__ unsigned pk2bf(float a, float b) {
  return (unsigned)f2bf(a) | ((unsigned)f2bf(b) << 16);
}

// K element (bh, spos, d) -> offset in KV-tiled layout (ushort units).
// Tile = 32 keys, 32KB: [K: kt(2)][d8(8)][ll(16)][lg(4)][e(8)] then V 16KB.
__device__ __forceinline__ size_t kaddr(int bh, int spos, int d) {
  return ((size_t)(bh * 64 + (spos >> 5))) * 16384
       + ((spos >> 4) & 1) * 4096 + (d >> 5) * 512 + (spos & 15) * 32
       + ((d >> 3) & 3) * 8 + (d & 7);
}

// ---------- K1: gates (ig/fg) + bf16 Q copy + K tiled copy ------------------
__global__ __launch_bounds__(512)
void gates_kernel(const float* __restrict__ q, const float* __restrict__ k,
                  const float* __restrict__ v,
                  const float* __restrict__ wi, const float* __restrict__ bi,
                  const float* __restrict__ wf, const float* __restrict__ bf,
                  float* __restrict__ ig, float* __restrict__ fg,
                  unsigned short* __restrict__ Qb, unsigned short* __restrict__ KVt)
{
  const int w = threadIdx.x >> 6, l = threadIdx.x & 63;
  const int bs0 = blockIdx.x * 16;
  const int bsr0 = bs0 + w * 2, bsr1 = bsr0 + 1;
  float p[2][8];
#pragma unroll
  for (int rr = 0; rr < 2; ++rr)
#pragma unroll
    for (int g2 = 0; g2 < 8; ++g2) p[rr][g2] = 0.f;

#pragma unroll
  for (int chunk = 0; chunk < 12; ++chunk) {
    const int idx = l * 4 + chunk * 256;     // 0..3071
    const float* src; int off;
    if (idx < 1024)       { src = q; off = idx; }
    else if (idx < 2048)  { src = k; off = idx - 1024; }
    else                  { src = v; off = idx - 2048; }
    float4 g0 = *(const float4*)(src + (size_t)bsr0 * Hx + off);
    float4 g1 = *(const float4*)(src + (size_t)bsr1 * Hx + off);
#pragma unroll
    for (int h = 0; h < 4; ++h) {
      float4 wiv = *(const float4*)(wi + h * 3 * Hx + idx);
      float4 wfv = *(const float4*)(wf + h * 3 * Hx + idx);
      p[0][h]     += g0.x*wiv.x + g0.y*wiv.y + g0.z*wiv.z + g0.w*wiv.w;
      p[1][h]     += g1.x*wiv.x + g1.y*wiv.y + g1.z*wiv.z + g1.w*wiv.w;
      p[0][4 + h] += g0.x*wfv.x + g0.y*wfv.y + g0.z*wfv.z + g0.w*wfv.w;
      p[1][4 + h] += g1.x*wfv.x + g1.y*wfv.y + g1.z*wfv.z + g1.w*wfv.w;
    }
    if (idx < 2048) {
      const int hh = off >> 8, dd = off & 255;
      const int b0 = bsr0 >> 11, s0p = bsr0 & 2047;
      const int b1 = bsr1 >> 11, s1p = bsr1 & 2047;
      ushort4 o0; o0.x=f2bf(g0.x); o0.y=f2bf(g0.y); o0.z=f2bf(g0.z); o0.w=f2bf(g0.w);
      ushort4 o1; o1.x=f2bf(g1.x); o1.y=f2bf(g1.y); o1.z=f2bf(g1.z); o1.w=f2bf(g1.w);
      if (idx < 1024) {
        *(ushort4*)(Qb + ((size_t)(b0 * NHx + hh) * Sx + s0p) * DHx + dd) = o0;
        *(ushort4*)(Qb + ((size_t)(b1 * NHx + hh) * Sx + s1p) * DHx + dd) = o1;
      } else {
        *(ushort4*)(KVt + kaddr(b0 * NHx + hh, s0p, dd)) = o0;
        *(ushort4*)(KVt + kaddr(b1 * NHx + hh, s1p, dd)) = o1;
      }
    }
  }
#pragma unroll
  for (int rr = 0; rr < 2; ++rr)
#pragma unroll
    for (int g2 = 0; g2 < 8; ++g2) {
      float x = p[rr][g2];
      x += __shfl_xor(x, 1);  x += __shfl_xor(x, 2);  x += __shfl_xor(x, 4);
      x += __shfl_xor(x, 8);  x += __shfl_xor(x, 16); x += __shfl_xor(x, 32);
      p[rr][g2] = x;
    }
  if (l == 0) {
#pragma unroll
    for (int rr = 0; rr < 2; ++rr) {
      const int bs = bs0 + w * 2 + rr;
      const int b = bs >> 11, spos = bs & 2047;
#pragma unroll
      for (int h = 0; h < 4; ++h) {
        ig[(size_t)(b * NHx + h) * Sx + spos] = p[rr][h] + bi[h];
        fg[(size_t)(b * NHx + h) * Sx + spos] = p[rr][4 + h] + bf[h];
      }
    }
  }
}

// ---------- K2: per-(b,h) scan: a[], M[], exp(-m)[] -------------------------
__global__ __launch_bounds__(256)
void scan_kernel(const float* __restrict__ ig, const float* __restrict__ fg,
                 float* __restrict__ av, float* __restrict__ Mv,
                 float* __restrict__ nfv)
{
  const int bh = blockIdx.x;
  const int t  = threadIdx.x;
  const size_t base = (size_t)bh * Sx;
  const int s0 = t * 8;
  float4 f0 = *(const float4*)(fg + base + s0);
  float4 f1 = *(const float4*)(fg + base + s0 + 4);
  float4 g0 = *(const float4*)(ig + base + s0);
  float4 g1 = *(const float4*)(ig + base + s0 + 4);
  float xf[8] = {f0.x,f0.y,f0.z,f0.w,f1.x,f1.y,f1.z,f1.w};
  float xi[8] = {g0.x,g0.y,g0.z,g0.w,g1.x,g1.y,g1.z,g1.w};
  float ps[8];
  float run = 0.0f;
#pragma unroll
  for (int i = 0; i < 8; ++i) { run += logsigf(xf[i]); ps[i] = run; }
  __shared__ float ssum[256];
  __shared__ float smax[256];
  ssum[t] = run;
  __syncthreads();
  for (int st = 1; st < 256; st <<= 1) {
    float addv = (t >= st) ? ssum[t - st] : 0.0f;
    __syncthreads();
    ssum[t] += addv;
    __syncthreads();
  }
  const float exs = (t > 0) ? ssum[t - 1] : 0.0f;
  float a[8], pm[8];
  float rm = -INFINITY;
#pragma unroll
  for (int i = 0; i < 8; ++i) {
    a[i] = xi[i] - (exs + ps[i]);
    rm = fmaxf(rm, a[i]);
    pm[i] = rm;
  }
  smax[t] = rm;
  __syncthreads();
  for (int st = 1; st < 256; st <<= 1) {
    float mv = (t >= st) ? smax[t - st] : -INFINITY;
    __syncthreads();
    smax[t] = fmaxf(smax[t], mv);
    __syncthreads();
  }
  const float exm = (t > 0) ? smax[t - 1] : -INFINITY;
#pragma unroll
  for (int i = 0; i < 8; ++i) {
    const float M = fmaxf(exm, pm[i]);
    const float F = exs + ps[i];
    av[base + s0 + i]  = a[i];
    Mv[base + s0 + i]  = M;
    nfv[base + s0 + i] = expf(-(F + M));
  }
}

// ---------- K3: V -> tiled bf16 fragment layout into KVt --------------------
__global__ __launch_bounds__(256)
void vtrans_kernel(const float* __restrict__ v, unsigned short* __restrict__ KVt)
{
  __shared__ float t32[32][260];
  const int tile = blockIdx.x, bh = blockIdx.y, b = bh >> 2, h = bh & 3;
  const int t = threadIdx.x;
  {
    const int r = t >> 3, dc = (t & 7) * 32;
    const float* p = v + ((size_t)b * Sx + tile * 32 + r) * Hx + h * DHx + dc;
#pragma unroll
    for (int i = 0; i < 8; ++i) {
      float4 x = *(const float4*)(p + i * 4);
      t32[r][dc + i*4 + 0] = x.x; t32[r][dc + i*4 + 1] = x.y;
      t32[r][dc + i*4 + 2] = x.z; t32[r][dc + i*4 + 3] = x.w;
    }
  }
  __syncthreads();
  {
    const int ds2 = t >> 4, llv = t & 15;
    const int d = ds2 * 16 + llv;
    unsigned short* dst = KVt + ((size_t)(bh * 64 + tile)) * 16384 + 8192
                        + ds2 * 512 + llv * 32;
#pragma unroll
    for (int g = 0; g < 8; ++g) {
      ushort4 o;
      o.x = f2bf(t32[g*4+0][d]); o.y = f2bf(t32[g*4+1][d]);
      o.z = f2bf(t32[g*4+2][d]); o.w = f2bf(t32[g*4+3][d]);
      *(ushort4*)(dst + g * 4) = o;
    }
  }
}

// ---------- K4a: pass1 — BQ=256, wave=32 q-rows, pipelined LDS staging -------
// 512 thr = 8 waves; wave owns 32 q-rows (2 q-groups); each K/V LDS read feeds
// 2 MFMAs. Unit = (bh, ti 0..7, chunk): 32 uniform units/bh (8-11 tiles each)
// -> grid 256 blocks, 1/CU, XCD-pinned by bh. R12's barrier/waitcnt skeleton.
__global__ __launch_bounds__(512, 2)
void mlstm_pass1(const unsigned short* __restrict__ Qb,
                 const unsigned short* __restrict__ KVt,
                 const float* __restrict__ av, const float* __restrict__ Mv,
                 const float* __restrict__ nfv, const float* __restrict__ lnw,
                 unsigned short* __restrict__ part, float* __restrict__ rsums,
                 float* __restrict__ out)
{
  __shared__ __align__(16) unsigned short KVls[2][16384];  // 64 KB
  __shared__ float avls[384];                              // 1.5 KB

  const int bh = blockIdx.x, b = bh >> 2, h = bh & 3;
  const int u = blockIdx.y;
  int ti, c, nc;
  if (u < 8)       { ti = 7; c = u;      nc = 8; }
  else if (u < 14) { ti = 6; c = u - 8;  nc = 6; }
  else if (u < 19) { ti = 5; c = u - 14; nc = 5; }
  else if (u < 23) { ti = 4; c = u - 19; nc = 4; }
  else if (u < 26) { ti = 3; c = u - 23; nc = 3; }
  else if (u < 29) { ti = 2; c = u - 26; nc = 3; }
  else if (u < 31) { ti = 1; c = u - 29; nc = 2; }
  else             { ti = 0; c = 0;      nc = 1; }
  const int ntiles = 8 * ti + 8;
  const int tj0 = c * ntiles / nc, tje = (c + 1) * ntiles / nc;
  const int i0 = ti * 256;
  const int key0 = tj0 * 32;
  const int pidx = bh * 31 + u;

  const int tid = threadIdx.x;
  const int w = tid >> 6, l = tid & 63;
  const int lg = l >> 4, ll = l & 15;
  const size_t bhS = (size_t)bh * Sx;

  // av preload into LDS
  for (int i = tid; i < (tje - tj0) * 32; i += 512) avls[i] = av[bhS + key0 + i];

  // Q B-frags for this wave's 32 q-rows (2 groups of 16)
  bf16x8 qf[2][8];
  float Mq[2];
#pragma unroll
  for (int qg = 0; qg < 2; ++qg) {
    const int qrow = i0 + w * 32 + qg * 16 + ll;
    const unsigned short* qp = Qb + (bhS + qrow) * DHx + lg * 8;
#pragma unroll
    for (int d8 = 0; d8 < 8; ++d8) qf[qg][d8] = *(const bf16x8*)(qp + d8 * 32);
    Mq[qg] = Mv[bhS + qrow];
  }

  f32x4 acc[2][16];
#pragma unroll
  for (int qg = 0; qg < 2; ++qg)
#pragma unroll
    for (int jt = 0; jt < 16; ++jt) acc[qg][jt] = f32x4{0, 0, 0, 0};
  float rsum[2] = {0.f, 0.f};

  const unsigned short* kvb = KVt + (size_t)(bh * 64) * 16384;
  uint4 r0, r1, r2, r3;

#define LOADR(tj) {                                                        \
    const unsigned short* _s = kvb + (size_t)(tj) * 16384 + tid * 8;       \
    r0 = *(const uint4*)(_s);          r1 = *(const uint4*)(_s + 4096);    \
    r2 = *(const uint4*)(_s + 8192);   r3 = *(const uint4*)(_s + 12288); }
#define WRITER(buf) {                                                      \
    char* _d = (char*)&KVls[buf][0] + tid * 16;                            \
    *(uint4*)(_d)         = r0; *(uint4*)(_d + 8192)  = r1;                \
    *(uint4*)(_d + 16384) = r2; *(uint4*)(_d + 24576) = r3; }

  LOADR(tj0);
  asm volatile("s_waitcnt vmcnt(0)" ::: "memory");
  WRITER(0);
  LOADR(tj0 + 1);                       // every chunk has >= 8 tiles
  asm volatile("s_waitcnt lgkmcnt(0)" ::: "memory");
  __builtin_amdgcn_s_barrier();

  for (int tj = tj0; tj < tje; ++tj) {
    const int cur = (tj - tj0) & 1;
    asm volatile("s_waitcnt vmcnt(0)" ::: "memory");
    if (tj + 1 < tje) WRITER(cur ^ 1);          // stage tj+1 into other buf
    if (tj + 2 < tje) LOADR(tj + 2);            // issue next loads
    __builtin_amdgcn_sched_barrier(0);

    const char* KB = (const char*)&KVls[cur][0];
    const char* VB = KB + 16384;
    const int rel = (tj - tj0) * 32;

    // ---- QK: two 16-key subtiles; each K read feeds both q-groups ----
    f32x4 st[2][2];
#pragma unroll
    for (int kt = 0; kt < 2; ++kt)
#pragma unroll
      for (int qg = 0; qg < 2; ++qg) st[kt][qg] = f32x4{0, 0, 0, 0};
#pragma unroll
    for (int d8 = 0; d8 < 8; ++d8) {
      const int fo = d8 * 1024 + ll * 64 + lg * 16;
      bf16x8 k0 = *(const bf16x8*)(KB + fo);
      bf16x8 k1 = *(const bf16x8*)(KB + 8192 + fo);
      st[0][0] = __builtin_amdgcn_mfma_f32_16x16x32_bf16(k0, qf[0][d8], st[0][0], 0, 0, 0);
      st[0][1] = __builtin_amdgcn_mfma_f32_16x16x32_bf16(k0, qf[1][d8], st[0][1], 0, 0, 0);
      st[1][0] = __builtin_amdgcn_mfma_f32_16x16x32_bf16(k1, qf[0][d8], st[1][0], 0, 0, 0);
      st[1][1] = __builtin_amdgcn_mfma_f32_16x16x32_bf16(k1, qf[1][d8], st[1][1], 0, 0, 0);
    }
    const f32x4 a4_0 = *(const f32x4*)&avls[rel + lg * 4];
    const f32x4 a4_1 = *(const f32x4*)&avls[rel + 16 + lg * 4];

    // ---- transform per q-group: mask+decay+rsum; pack; redistribute ----
    const int j0 = tj * 32;
    bf16x8 pb[2];
#pragma unroll
    for (int qg = 0; qg < 2; ++qg) {
      const int qrow = i0 + w * 32 + qg * 16 + ll;
      unsigned x0[4], x1[4];
#pragma unroll
      for (int kt = 0; kt < 2; ++kt) {
        const f32x4 s = st[kt][qg];
        const f32x4 a = kt ? a4_1 : a4_0;
        const int kb = j0 + kt * 16 + 4 * lg;
        float p0 = (kb + 0 <= qrow) ? s[0] * (RSQ * __expf(a[0] - Mq[qg])) : 0.f;
        float p1 = (kb + 1 <= qrow) ? s[1] * (RSQ * __expf(a[1] - Mq[qg])) : 0.f;
        float p2 = (kb + 2 <= qrow) ? s[2] * (RSQ * __expf(a[2] - Mq[qg])) : 0.f;
        float p3 = (kb + 3 <= qrow) ? s[3] * (RSQ * __expf(a[3] - Mq[qg])) : 0.f;
        rsum[qg] += (p0 + p1) + (p2 + p3);
        unsigned lo = pk2bf(p0, p1), hi = pk2bf(p2, p3);
        unsigned plo = __shfl_xor(lo, 16), phi = __shfl_xor(hi, 16);
        bool ge = ((lg & 1) == 0);
        unsigned* x = kt ? x1 : x0;
        x[0] = ge ? lo : plo;  x[1] = ge ? hi : phi;
        x[2] = ge ? plo : lo;  x[3] = ge ? phi : hi;
      }
      unsigned pw0, pw1, pw2, pw3;
#pragma unroll
      for (int j = 0; j < 4; ++j) {
        unsigned yA = __shfl_xor(x0[j], 32);
        unsigned yB = __shfl_xor(x1[j], 32);
        unsigned r = (lg == 0) ? x0[j] : (lg == 1) ? yA : (lg == 2) ? yB : x1[j];
        if (j == 0) pw0 = r; else if (j == 1) pw1 = r; else if (j == 2) pw2 = r; else pw3 = r;
      }
      u32x4 w4 = {pw0, pw1, pw2, pw3};
      pb[qg] = __builtin_bit_cast(bf16x8, w4);
    }

    // ---- PV: each V read feeds both q-groups ----
#pragma unroll
    for (int ds2 = 0; ds2 < 16; ++ds2) {
      bf16x8 vf = *(const bf16x8*)(VB + ds2 * 1024 + ll * 64 + lg * 16);
      acc[0][ds2] = __builtin_amdgcn_mfma_f32_16x16x32_bf16(vf, pb[0], acc[0][ds2], 0, 0, 0);
      acc[1][ds2] = __builtin_amdgcn_mfma_f32_16x16x32_bf16(vf, pb[1], acc[1][ds2], 0, 0, 0);
    }

    asm volatile("s_waitcnt lgkmcnt(0)" ::: "memory");
    __builtin_amdgcn_sched_barrier(0);
    __builtin_amdgcn_s_barrier();
  }
#undef LOADR
#undef WRITER

  // ---- epilogue per q-group ----
#pragma unroll
  for (int qg = 0; qg < 2; ++qg) {
    const int qloc = w * 32 + qg * 16 + ll;
    float rs = rsum[qg];
    rs += __shfl_xor(rs, 16); rs += __shfl_xor(rs, 32);
    if (nc == 1) {
      // direct: normalizer + group-LN
      float s1 = 0.f, s2 = 0.f;
#pragma unroll
      for (int jt = 0; jt < 16; ++jt)
#pragma unroll
        for (int r = 0; r < 4; ++r) {
          const float x = acc[qg][jt][r];
          s1 += x; s2 += x * x;
        }
      s1 += __shfl_xor(s1, 16); s1 += __shfl_xor(s1, 32);
      s2 += __shfl_xor(s2, 16); s2 += __shfl_xor(s2, 32);
      const int qrow = i0 + qloc;
      const float nf = nfv[bhS + qrow];
      const float inv = 1.f / (fmaxf(fabsf(rs), nf) + 1e-6f);
      const float mean = s1 * inv * (1.f / 256.f);
      const float ex2  = s2 * inv * inv * (1.f / 256.f);
      const float var  = ex2 - mean * mean;
      const float rstd = rsqrtf(var + 1e-5f);
      float* op = out + ((size_t)b * Sx + qrow) * Hx + h * DHx;
#pragma unroll
      for (int jt = 0; jt < 16; ++jt) {
        const int dbase = jt * 16 + lg * 4;
        f32x4 lw = *(const f32x4*)(lnw + h * DHx + dbase);
        float4 o;
        o.x = (acc[qg][jt][0] * inv - mean) * rstd * (1.f + lw[0]);
        o.y = (acc[qg][jt][1] * inv - mean) * rstd * (1.f + lw[1]);
        o.z = (acc[qg][jt][2] * inv - mean) * rstd * (1.f + lw[2]);
        o.w = (acc[qg][jt][3] * inv - mean) * rstd * (1.f + lw[3]);
        *(float4*)(op + dbase) = o;
      }
    } else {
      unsigned short* pO = part + (size_t)pidx * 65536 + qloc * 256 + lg * 4;
#pragma unroll
      for (int ds2 = 0; ds2 < 16; ++ds2) {
        ushort4 o;
        o.x = f2bf(acc[qg][ds2][0]); o.y = f2bf(acc[qg][ds2][1]);
        o.z = f2bf(acc[qg][ds2][2]); o.w = f2bf(acc[qg][ds2][3]);
        *(ushort4*)(pO + ds2 * 16) = o;
      }
      if (lg == 0) rsums[pidx * 256 + qloc] = rs;
    }
  }
}

// ---------- K4b: pass2 — combine nc chunks + normalizer + group-LN ----------
__global__ __launch_bounds__(512)
void mlstm_pass2(const unsigned short* __restrict__ part,
                 const float* __restrict__ rsums,
                 const float* __restrict__ nfv, const float* __restrict__ lnw,
                 float* __restrict__ out)
{
  const int bh = blockIdx.x, b = bh >> 2, h = bh & 3;
  const int ti = 1 + (int)blockIdx.y;          // 1..7
  const int h2 = blockIdx.z;                   // row half
  const int nc_t[8] = {1, 2, 3, 3, 4, 5, 6, 8};
  const int u0_t[8] = {31, 29, 26, 23, 19, 14, 8, 0};
  const int nc = nc_t[ti], u0 = u0_t[ti];
  const int p0 = bh * 31 + u0;
  const int tid = threadIdx.x;
  const int ql = h2 * 128 + (tid >> 2), dc = (tid & 3) * 64;
  const int qrow = ti * 256 + ql;
  const size_t bhS = (size_t)bh * Sx;

  float o[64];
#pragma unroll
  for (int j = 0; j < 64; ++j) o[j] = 0.f;
  float rs = 0.f;
  for (int cc = 0; cc < nc; ++cc) {
    const unsigned short* A = part + (size_t)(p0 + cc) * 65536 + ql * 256 + dc;
#pragma unroll
    for (int j = 0; j < 8; ++j) {
      bf16x8 va = *(const bf16x8*)(A + j * 8);
#pragma unroll
      for (int r = 0; r < 8; ++r) o[j * 8 + r] += bf2f((unsigned short)va[r]);
    }
    rs += rsums[(p0 + cc) * 256 + ql];
  }
  const float nf = nfv[bhS + qrow];
  const float inv = 1.f / (fmaxf(fabsf(rs), nf) + 1e-6f);
  float s1 = 0.f, s2 = 0.f;
#pragma unroll
  for (int j = 0; j < 64; ++j) {
    const float x = o[j] * inv;
    o[j] = x; s1 += x; s2 += x * x;
  }
  s1 += __shfl_xor(s1, 1); s1 += __shfl_xor(s1, 2);
  s2 += __shfl_xor(s2, 1); s2 += __shfl_xor(s2, 2);
  const float mean = s1 * (1.f / 256.f);
  const float var  = s2 * (1.f / 256.f) - mean * mean;
  const float rstd = rsqrtf(var + 1e-5f);
  float* op = out + ((size_t)b * Sx + qrow) * Hx + h * DHx + dc;
#pragma unroll
  for (int j = 0; j < 16; ++j) {
    f32x4 lw = *(const f32x4*)(lnw + h * DHx + dc + j * 4);
    float4 ov;
    ov.x = (o[j*4+0] - mean) * rstd * (1.f + lw[0]);
    ov.y = (o[j*4+1] - mean) * rstd * (1.f + lw[1]);
    ov.z = (o[j*4+2] - mean) * rstd * (1.f + lw[2]);
    ov.w = (o[j*4+3] - mean) * rstd * (1.f + lw[3]);
    *(float4*)(op + j * 4) = ov;
  }
}

extern "C" void kernel_launch(void* const* d_in, const int* in_sizes, int n_in,
                              void* d_out, int out_size, void* d_ws, size_t ws_size,
                              hipStream_t stream) {
  const float* q   = (const float*)d_in[0];
  const float* k   = (const float*)d_in[1];
  const float* v   = (const float*)d_in[2];
  const float* wi  = (const float*)d_in[3];
  const float* bi  = (const float*)d_in[4];
  const float* wf  = (const float*)d_in[5];
  const float* bf  = (const float*)d_in[6];
  const float* lnw = (const float*)d_in[7];
  float* out = (float*)d_out;
  float* ws  = (float*)d_ws;

  const int G = Bx * NHx * Sx;         // 16384
  float* ig  = ws;
  float* fg  = ws + (size_t)G;
  float* av  = ws + (size_t)2 * G;
  float* Mv  = ws + (size_t)3 * G;
  float* nfv = ws + (size_t)4 * G;
  unsigned short* Qb   = (unsigned short*)(ws + (size_t)5 * G);  // 16 MB
  unsigned short* KVt  = Qb + (size_t)8388608;                   // 16 MB tiled KV
  unsigned short* part = KVt + (size_t)8388608;                  // 31 MB partials
  float* rsums = (float*)(part + (size_t)16252928);              // 254 KB
  // total ws use: ~64 MB

  gates_kernel<<<Bx * Sx / 16, 512, 0, stream>>>(q, k, v, wi, bi, wf, bf, ig, fg, Qb, KVt);
  scan_kernel<<<Bx * NHx, 256, 0, stream>>>(ig, fg, av, Mv, nfv);
  dim3 gT(64, Bx * NHx);
  vtrans_kernel<<<gT, 256, 0, stream>>>(v, KVt);
  dim3 g1(Bx * NHx, 32);               // x = bh (XCD pinned), y = unit
  mlstm_pass1<<<g1, 512, 0, stream>>>(Qb, KVt, av, Mv, nfv, lnw, part, rsums, out);
  dim3 g2(Bx * NHx, 7, 2);
  mlstm_pass2<<<g2, 512, 0, stream>>>(part, rsums, nfv, lnw, out);
}